// Round 20
// baseline (21677.660 us; speedup 1.0000x reference)
//
#include <hip/hip_runtime.h>
#include <stdint.h>

#define T_STEPS 4096
#define IN_DIM  1024
#define H_DIM   2048
#define OUT_DIM 512
#define W_STRIDE 3072        // IN + H
#define NBLK    256          // one persistent block per CU
#define NTHR    512          // 8 waves/block -> 2 waves/SIMD
#define POLL_GUARD 65536     // bounded spin before declaring wedge

typedef __attribute__((ext_vector_type(4))) float floatx4;

__device__ __forceinline__ float fsigmoid(float v) {
  return __builtin_amdgcn_rcpf(1.f + __expf(-v));
}
__device__ __forceinline__ float ftanh(float v) {
  return 1.f - 2.f * __builtin_amdgcn_rcpf(1.f + __expf(2.f * v));
}
__device__ __forceinline__ unsigned umin2(unsigned a, unsigned b) {
  return a < b ? a : b;
}

// ---------------------------------------------------------------------------
// Persistent fused LSTM scan -- R13: ROWS<->WAVES decomposition.
//
// R12 (x-overlap) was null (-0.6%) despite verifiably landing (LDS 12.8->8.7KB,
// conflicts -67%): the removed tail items weren't on the critical path. The
// untouched tail items between h-FMA and publish were: shuffle-reduce ->
// red[] LDS write -> sync2 -> wave-0-only [K]. This round deletes them all:
// wave w owns ROW row0+w entirely (lane l covers col-quads 4l+256i for all
// 4 gates: 16 x-cols + 32 h-cols = same 192 weight floats). The wave's
// 6-step shfl reduce leaves ALL 4 gate sums in its lane 0, which computes
// the gates and publishes immediately. 1 barrier/step (was 2), no red[],
// c-state in a lane-0 register. hl is a double-buffered LINEAR [2][2048]
// (stage-after-detect makes ping-pong safe: a wave re-stages buffer t&1
// only after detecting all tags >= t+2, which implies every wave finished
// reading it). All LDS patterns are canonical consecutive-lane accesses.
//
// Falsified so far: coherent-point line contention (R9 8x-replication null),
// MALL weight streaming (R10: VGPR=128 + FETCH 0.4GB -> weights in AGPRs),
// intra-poll serialization (R11 -4.9%), staging/x-FMA tail (R12 -0.6%).
// Handshake (29.1 -> 17.8 -> 16.7ms): single-hop 8B (tag<<32|float) packet,
// relaxed agent-scope store; poll exits on min(tag)>=t (monotone-safe:
// polled slots hold only t-2 or t). Ping-pong on t&1. Bounded bailout.
// ---------------------------------------------------------------------------
#define FMA4(acc, wq, v) do {                                                 \
    acc = fmaf(wq.x, v.x, acc); acc = fmaf(wq.y, v.y, acc);                   \
    acc = fmaf(wq.z, v.z, acc); acc = fmaf(wq.w, v.w, acc); } while (0)
#define GDECL(g) floatx4 wx##g##_0, wx##g##_1, wx##g##_2, wx##g##_3,          \
    wh##g##_0, wh##g##_1, wh##g##_2, wh##g##_3,                               \
    wh##g##_4, wh##g##_5, wh##g##_6, wh##g##_7
#define GLOAD(g, P) do {                                                      \
    wx##g##_0 = *(const floatx4*)((P) +    0);                                \
    wx##g##_1 = *(const floatx4*)((P) +  256);                                \
    wx##g##_2 = *(const floatx4*)((P) +  512);                                \
    wx##g##_3 = *(const floatx4*)((P) +  768);                                \
    wh##g##_0 = *(const floatx4*)((P) + 1024);                                \
    wh##g##_1 = *(const floatx4*)((P) + 1280);                                \
    wh##g##_2 = *(const floatx4*)((P) + 1536);                                \
    wh##g##_3 = *(const floatx4*)((P) + 1792);                                \
    wh##g##_4 = *(const floatx4*)((P) + 2048);                                \
    wh##g##_5 = *(const floatx4*)((P) + 2304);                                \
    wh##g##_6 = *(const floatx4*)((P) + 2560);                                \
    wh##g##_7 = *(const floatx4*)((P) + 2816); } while (0)
#define GPIN(g) asm volatile("" : "+v"(wx##g##_0), "+v"(wx##g##_1),           \
    "+v"(wx##g##_2), "+v"(wx##g##_3), "+v"(wh##g##_0), "+v"(wh##g##_1),       \
    "+v"(wh##g##_2), "+v"(wh##g##_3), "+v"(wh##g##_4), "+v"(wh##g##_5),       \
    "+v"(wh##g##_6), "+v"(wh##g##_7))
#define HFMA(i) do {                                                          \
    const floatx4 v = *(const floatx4*)(hr + (i) * 256);                      \
    FMA4(a0, wh0_##i, v); FMA4(a1, wh1_##i, v);                               \
    FMA4(a2, wh2_##i, v); FMA4(a3, wh3_##i, v); } while (0)
#define RED(a) do {                                                           \
    a += __shfl_down(a, 32, 64); a += __shfl_down(a, 16, 64);                 \
    a += __shfl_down(a, 8, 64);  a += __shfl_down(a, 4, 64);                  \
    a += __shfl_down(a, 2, 64);  a += __shfl_down(a, 1, 64); } while (0)

__global__ __launch_bounds__(NTHR, 2)
void lstm_scan(const float* __restrict__ Wi, const float* __restrict__ Wf,
               const float* __restrict__ Wo, const float* __restrict__ Wc,
               const float* __restrict__ bi, const float* __restrict__ bff,
               const float* __restrict__ bo, const float* __restrict__ bc,
               const float* __restrict__ x,
               unsigned long long* __restrict__ hcomm,  // [2][H_DIM] packets
               float* __restrict__ hbuf,                // [H_DIM] final h
               float* __restrict__ cbuf)                // [H_DIM] final c
{
  __shared__ float hl[2][H_DIM];  // double-buffered h_t, LINEAR (16 KB)

  const int tid = threadIdx.x;
  const int b   = blockIdx.x;
  const int w   = tid >> 6;       // wave id 0..7  -> owns row row0+w
  const int l   = tid & 63;       // lane: col-quads 4l+256i
  const int row = (b << 3) + w;

  const size_t wb = (size_t)row * W_STRIDE + ((size_t)l << 2);
  GDECL(0); GDECL(1); GDECL(2); GDECL(3);
  GLOAD(0, Wi + wb); GLOAD(1, Wf + wb); GLOAD(2, Wo + wb); GLOAD(3, Wc + wb);
  GPIN(0); GPIN(1); GPIN(2); GPIN(3);

  // per-row scalars (wave-uniform; only lane 0's copy is consumed)
  const float bia = bi[row], bfa = bff[row], boa = bo[row], bca = bc[row];
  float creg = 0.f, hlast = 0.f;
  int   alive = 1;                // cleared if a poll exhausts POLL_GUARD

  for (int t = 0; t < T_STEPS; ++t) {
    // [X] x loads: lane l reads quads at 4l+256i -- fully coalesced 1KB/instr
    const float* xp = x + ((size_t)t << 10) + (l << 2);
    const floatx4 x0 = *(const floatx4*)(xp);
    const floatx4 x1 = *(const floatx4*)(xp + 256);
    const floatx4 x2 = *(const floatx4*)(xp + 512);
    const floatx4 x3 = *(const floatx4*)(xp + 768);

    // [P] poll issue: 4 independent relaxed loads, in flight during [F-x]
    unsigned long long* hb = hcomm + ((size_t)(t & 1) << 11);
    const unsigned tt = (unsigned)t;
    unsigned long long p0, p1, p2, p3;
    p0 = __hip_atomic_load(&hb[tid], __ATOMIC_RELAXED,
                           __HIP_MEMORY_SCOPE_AGENT);
    p1 = __hip_atomic_load(&hb[tid + 512], __ATOMIC_RELAXED,
                           __HIP_MEMORY_SCOPE_AGENT);
    p2 = __hip_atomic_load(&hb[tid + 1024], __ATOMIC_RELAXED,
                           __HIP_MEMORY_SCOPE_AGENT);
    p3 = __hip_atomic_load(&hb[tid + 1536], __ATOMIC_RELAXED,
                           __HIP_MEMORY_SCOPE_AGENT);

    // [F-x] 64 h-independent FMAs overlap the poll flight
    float a0 = 0.f, a1 = 0.f, a2 = 0.f, a3 = 0.f;
    FMA4(a0, wx0_0, x0); FMA4(a0, wx0_1, x1); FMA4(a0, wx0_2, x2); FMA4(a0, wx0_3, x3);
    FMA4(a1, wx1_0, x0); FMA4(a1, wx1_1, x1); FMA4(a1, wx1_2, x2); FMA4(a1, wx1_3, x3);
    FMA4(a2, wx2_0, x0); FMA4(a2, wx2_1, x1); FMA4(a2, wx2_2, x2); FMA4(a2, wx2_3, x3);
    FMA4(a3, wx3_0, x0); FMA4(a3, wx3_1, x1); FMA4(a3, wx3_2, x2); FMA4(a3, wx3_3, x3);

    // [B] tag check + batched re-poll
    {
      unsigned mn = umin2(umin2((unsigned)(p0 >> 32), (unsigned)(p1 >> 32)),
                          umin2((unsigned)(p2 >> 32), (unsigned)(p3 >> 32)));
      int guard = 0;
      while (alive && mn < tt) {
        if (++guard > POLL_GUARD) { alive = 0; break; }  // wedge -> bail loud
        __builtin_amdgcn_s_sleep(1);
        p0 = __hip_atomic_load(&hb[tid], __ATOMIC_RELAXED,
                               __HIP_MEMORY_SCOPE_AGENT);
        p1 = __hip_atomic_load(&hb[tid + 512], __ATOMIC_RELAXED,
                               __HIP_MEMORY_SCOPE_AGENT);
        p2 = __hip_atomic_load(&hb[tid + 1024], __ATOMIC_RELAXED,
                               __HIP_MEMORY_SCOPE_AGENT);
        p3 = __hip_atomic_load(&hb[tid + 1536], __ATOMIC_RELAXED,
                               __HIP_MEMORY_SCOPE_AGENT);
        mn = umin2(umin2((unsigned)(p0 >> 32), (unsigned)(p1 >> 32)),
                   umin2((unsigned)(p2 >> 32), (unsigned)(p3 >> 32)));
      }
    }

    // [D] stage linear (consecutive tid -> consecutive dwords, conflict-free)
    {
      float* hs = hl[t & 1];
      hs[tid]        = __uint_as_float((unsigned)p0);
      hs[tid + 512]  = __uint_as_float((unsigned)p1);
      hs[tid + 1024] = __uint_as_float((unsigned)p2);
      hs[tid + 1536] = __uint_as_float((unsigned)p3);
    }
    __syncthreads();   // sync1: h fully staged (only barrier per step)

    // [F-h] 128 FMAs; consecutive lanes read consecutive 16B -- canonical
    {
      const float* hr = hl[t & 1] + (l << 2);
      HFMA(0); HFMA(1); HFMA(2); HFMA(3);
      HFMA(4); HFMA(5); HFMA(6); HFMA(7);
    }

    // [R] wave-local reduce: all 4 gate sums land in lane 0 of this wave
    RED(a0); RED(a1); RED(a2); RED(a3);

    // [K] lane 0 of each wave: gates + state + publish (no barrier needed)
    if (l == 0) {
      const float pi = bia + a0;
      const float pf = bfa + a1;
      const float po = boa + a2;
      const float pc = bca + a3;
      const float iv = fsigmoid(pi);
      const float fv = fsigmoid(pf);
      const float ov = fsigmoid(po);
      const float ct = ftanh(pc);
      const float cn = fv * creg + iv * ct;
      creg = cn;
      const float hv = ov * ftanh(cn);
      hlast = hv;
      const unsigned long long pk =
          ((unsigned long long)(unsigned)(t + 1) << 32) |
          (unsigned long long)__float_as_uint(hv);
      __hip_atomic_store(&hcomm[(((size_t)((t + 1) & 1)) << 11) + row],
                         pk, __ATOMIC_RELAXED, __HIP_MEMORY_SCOPE_AGENT);
    }
    // no second barrier: hl is double-buffered, and stage-after-detect
    // guarantees no wave can overwrite a buffer that any wave still reads.
  }

  if (l == 0) {
    hbuf[row] = hlast;
    cbuf[row] = creg;
  }
}

// ---------------------------------------------------------------------------
// out[0:512] = W2 @ [h; c] + b2   (fp32 in, fp32 out)
// ---------------------------------------------------------------------------
__global__ __launch_bounds__(256)
void final_kernel(const float* __restrict__ W2, const float* __restrict__ b2,
                  const float* __restrict__ hfin, const float* __restrict__ cfin,
                  float* __restrict__ out)
{
  const int wv   = threadIdx.x >> 6;
  const int lane = threadIdx.x & 63;
  const int row  = (blockIdx.x << 2) + wv;
  const float* wr = W2 + (size_t)row * (2 * H_DIM);
  float acc = 0.f;
#pragma unroll 4
  for (int k = lane; k < H_DIM; k += 64) {
    acc = fmaf(wr[k], hfin[k], acc);
    acc = fmaf(wr[H_DIM + k], cfin[k], acc);
  }
#pragma unroll
  for (int off = 32; off > 0; off >>= 1) acc += __shfl_down(acc, off, 64);
  if (lane == 0) out[row] = acc + b2[row];
}

__global__ __launch_bounds__(256)
void copy_h_kernel(const float* __restrict__ hfin, float* __restrict__ out)
{
  const int i = blockIdx.x * 256 + threadIdx.x;
  if (i < H_DIM) out[OUT_DIM + i] = hfin[i];
}

// ---------------------------------------------------------------------------
extern "C" void kernel_launch(void* const* d_in, const int* in_sizes, int n_in,
                              void* d_out, int out_size, void* d_ws, size_t ws_size,
                              hipStream_t stream)
{
  const float* x   = (const float*)d_in[0];
  const float* Wi  = (const float*)d_in[1];
  const float* bi  = (const float*)d_in[2];
  const float* Wf  = (const float*)d_in[3];
  const float* bff = (const float*)d_in[4];
  const float* Wo  = (const float*)d_in[5];
  const float* bo  = (const float*)d_in[6];
  const float* Wc  = (const float*)d_in[7];
  const float* bc  = (const float*)d_in[8];
  const float* W2  = (const float*)d_in[9];
  const float* b2  = (const float*)d_in[10];
  float* out = (float*)d_out;

  // workspace: [hcomm 2*H u64 = 32 KB][hbuf H f32][cbuf H f32]  (~48 KB)
  char* ws = (char*)d_ws;
  unsigned long long* hcomm = (unsigned long long*)ws;
  float* hbuf = (float*)(ws + 2 * H_DIM * sizeof(unsigned long long));
  float* cbuf = hbuf + H_DIM;

  // zeroed packets == (tag 0, h=0): the valid initial state for step 0
  hipMemsetAsync(hcomm, 0, 2 * H_DIM * sizeof(unsigned long long), stream);

  lstm_scan<<<dim3(NBLK), dim3(NTHR), 0, stream>>>(
      Wi, Wf, Wo, Wc, bi, bff, bo, bc, x, hcomm, hbuf, cbuf);
  final_kernel<<<dim3(OUT_DIM / 4), 256, 0, stream>>>(W2, b2, hbuf, cbuf, out);
  copy_h_kernel<<<dim3((H_DIM + 255) / 256), 256, 0, stream>>>(hbuf, out);
}